// Round 12
// baseline (262.155 us; speedup 1.0000x reference)
//
#include <hip/hip_runtime.h>
#include <hip/hip_bf16.h>
#include <stdint.h>

#define BATCH 2
#define TT 2048
#define CC 1024
#define NH 16
#define HD 64

typedef __attribute__((ext_vector_type(8))) short short8;
typedef __attribute__((ext_vector_type(4))) short sh4;
typedef __attribute__((ext_vector_type(4))) float f32x4;
typedef __attribute__((ext_vector_type(2))) unsigned uint2v;

#define MFMA16 __builtin_amdgcn_mfma_f32_16x16x32_bf16
#define LOG2E 1.4426950408889634f

#if defined(__has_builtin)
#if __has_builtin(__builtin_amdgcn_exp2f)
#define EXP2(x) __builtin_amdgcn_exp2f(x)
#else
#define EXP2(x) __expf((x) * 0.6931471805599453f)
#endif
#else
#define EXP2(x) __expf((x) * 0.6931471805599453f)
#endif

__device__ __forceinline__ short f2bf(float f) {
  union { float f; unsigned u; } x;
  x.f = f;
  unsigned r = x.u + 0x7FFFu + ((x.u >> 16) & 1u);
  return (short)(r >> 16);
}

// ---------------------------------------------------------------------------
// Fused prep: blocks [0,2048) cast x fp32->bf16; [2048,2816) transpose W_attn;
// [2816,3072) transpose W_proj; [3072,3074) c = exp(mask) tables (bf16+f32).
// ---------------------------------------------------------------------------
__device__ __forceinline__ void transpose_cast_tile(
    const float* __restrict__ W, short* __restrict__ Wt, int K, int N,
    int n0, int k0, int tid) {
  __shared__ __align__(16) float Ls[64][68];
  {
    const int r = tid >> 4, c4 = (tid & 15) * 4;
#pragma unroll
    for (int p = 0; p < 4; ++p) {
      const float4 v = *reinterpret_cast<const float4*>(
          &W[(size_t)(k0 + r + p * 16) * N + n0 + c4]);
      *reinterpret_cast<float4*>(&Ls[r + p * 16][c4]) = v;
    }
  }
  __syncthreads();
  {
    const int n = tid >> 2;
    const int kk0 = (tid & 3) * 16;
#pragma unroll
    for (int half = 0; half < 2; ++half) {
      short8 o;
#pragma unroll
      for (int t = 0; t < 8; ++t) o[t] = f2bf(Ls[kk0 + half * 8 + t][n]);
      *reinterpret_cast<short8*>(&Wt[(size_t)(n0 + n) * K + k0 + kk0 + half * 8]) = o;
    }
  }
}

__global__ __launch_bounds__(256) void prep_fused(
    const float* __restrict__ x, short* __restrict__ xb,
    const float* __restrict__ W_attn, short* __restrict__ wat,
    const float* __restrict__ W_proj, short* __restrict__ wpt,
    const float* __restrict__ mask, short* __restrict__ cb16,
    float* __restrict__ cf32) {
  const int blk = blockIdx.x;
  const int tid = threadIdx.x;
  if (blk < 2048) {
    const int i = (blk * 256 + tid) * 8;
    const float4 a = *reinterpret_cast<const float4*>(&x[i]);
    const float4 b = *reinterpret_cast<const float4*>(&x[i + 4]);
    short8 o;
    o[0] = f2bf(a.x); o[1] = f2bf(a.y); o[2] = f2bf(a.z); o[3] = f2bf(a.w);
    o[4] = f2bf(b.x); o[5] = f2bf(b.y); o[6] = f2bf(b.z); o[7] = f2bf(b.w);
    *reinterpret_cast<short8*>(&xb[i]) = o;
  } else if (blk < 2816) {
    const int b2 = blk - 2048;
    transpose_cast_tile(W_attn, wat, CC, 3 * CC, (b2 % 48) * 64,
                        (b2 / 48) * 64, tid);
  } else if (blk < 3072) {
    const int b3 = blk - 2816;
    transpose_cast_tile(W_proj, wpt, CC, CC, (b3 % 16) * 64, (b3 / 16) * 64,
                        tid);
  } else {
    // c[b][s] = exp(mask[b][s]): bf16 (attn l-row) + f32 (vT scaling)
    const int b = blk - 3072;
    const int s = tid * 8;
    float c[8];
#pragma unroll
    for (int t = 0; t < 8; ++t) c[t] = __expf(mask[b * TT + s + t]);
    short8 o;
#pragma unroll
    for (int t = 0; t < 8; ++t) o[t] = f2bf(c[t]);
    *reinterpret_cast<short8*>(&cb16[b * TT + s]) = o;
#pragma unroll
    for (int t = 0; t < 8; ++t) cf32[b * TT + s + t] = c[t];
  }
}

// ---------------------------------------------------------------------------
// GEMM 64x128 tile, DOUBLE-BUFFERED (T3 minimum 2-phase, verified r8: -10us).
// LDS 48KB. Cols < QS get *(0.125*log2e). V third (n0>=2*CC, vT!=nullptr):
// tile scaled by c[s]=exp(mask) and written TRANSPOSED to vT[bh][d][s].
// ---------------------------------------------------------------------------
template <bool OUT_BF16>
__device__ __forceinline__ void gemm_bt_body(
    const short* __restrict__ A, const short* __restrict__ Bt,
    const float* __restrict__ bias, void* __restrict__ C,
    short* __restrict__ vT, const float* __restrict__ cV, int M, int N, int K,
    int QS) {
  __shared__ __align__(16) short SM[24576];  // 48KB arena
  short* As = SM;            // [2 buf][2 kh][64][32]  = 8192 shorts
  short* Bs = SM + 8192;     // [2 buf][2 kh][128][32] = 16384 shorts
  const int tid = threadIdx.x;
  const int w = tid >> 6, lane = tid & 63;
  const int quad = lane >> 4, l15 = lane & 15;
  const int m0 = blockIdx.y * 64, n0 = blockIdx.x * 128;

  f32x4 acc[4][2] = {};
  const int row16 = lane >> 2;
  const int c4 = (lane & 3) * 8;

  const int rbaseA = __builtin_amdgcn_readfirstlane(w * 16);
  const int rbaseB0 = __builtin_amdgcn_readfirstlane(w * 2 * 16);
  const int rbaseB1 = __builtin_amdgcn_readfirstlane((w * 2 + 1) * 16);

#define STAGE_TILE(buf, k0)                                                    \
  {                                                                            \
    _Pragma("unroll") for (int kh = 0; kh < 2; ++kh) {                         \
      const short* ga =                                                        \
          &A[(size_t)(m0 + rbaseA + row16) * K + (k0) + kh * 32 + c4];         \
      __builtin_amdgcn_global_load_lds(                                        \
          (const __attribute__((address_space(1))) void*)ga,                   \
          (__attribute__((address_space(3))) void*)                            \
              &As[(buf)*4096 + kh * 2048 + rbaseA * 32],                       \
          16, 0, 0);                                                           \
      const short* gb0 =                                                       \
          &Bt[(size_t)(n0 + rbaseB0 + row16) * K + (k0) + kh * 32 + c4];       \
      __builtin_amdgcn_global_load_lds(                                        \
          (const __attribute__((address_space(1))) void*)gb0,                  \
          (__attribute__((address_space(3))) void*)                            \
              &Bs[(buf)*8192 + kh * 4096 + rbaseB0 * 32],                      \
          16, 0, 0);                                                           \
      const short* gb1 =                                                       \
          &Bt[(size_t)(n0 + rbaseB1 + row16) * K + (k0) + kh * 32 + c4];       \
      __builtin_amdgcn_global_load_lds(                                        \
          (const __attribute__((address_space(1))) void*)gb1,                  \
          (__attribute__((address_space(3))) void*)                            \
              &Bs[(buf)*8192 + kh * 4096 + rbaseB1 * 32],                      \
          16, 0, 0);                                                           \
    }                                                                          \
  }

  STAGE_TILE(0, 0)
  __syncthreads();

  int cur = 0;
  for (int k0 = 0; k0 < K; k0 += 64) {
    if (k0 + 64 < K) STAGE_TILE(cur ^ 1, k0 + 64)

    short8 af[2][4], bfr[2][2];
#pragma unroll
    for (int kh = 0; kh < 2; ++kh) {
#pragma unroll
      for (int i = 0; i < 4; ++i)
        af[kh][i] = *reinterpret_cast<const short8*>(
            &As[cur * 4096 + kh * 2048 + (i * 16 + l15) * 32 + quad * 8]);
#pragma unroll
      for (int j = 0; j < 2; ++j)
        bfr[kh][j] = *reinterpret_cast<const short8*>(
            &Bs[cur * 8192 + kh * 4096 + (w * 32 + j * 16 + l15) * 32 +
                quad * 8]);
    }
#pragma unroll
    for (int kh = 0; kh < 2; ++kh)
#pragma unroll
      for (int i = 0; i < 4; ++i)
#pragma unroll
        for (int j = 0; j < 2; ++j)
          acc[i][j] = MFMA16(af[kh][i], bfr[kh][j], acc[i][j], 0, 0, 0);

    __syncthreads();
    cur ^= 1;
  }
#undef STAGE_TILE

  if (OUT_BF16 && vT != nullptr && n0 >= 2 * CC) {
    // V-tile: (acc+bias)*c[s] -> transposed vT[bh][d][s] via LDS.
    const int n0v = n0 - 2 * CC;
    const int b = m0 >> 11;
    const int s_batch = m0 & (TT - 1);
    short* Ls = SM;  // [128][88] = 11264 shorts <= 24576
#pragma unroll
    for (int i = 0; i < 4; ++i) {
      const int sl = i * 16 + quad * 4;
      const float4 cv = *reinterpret_cast<const float4*>(&cV[m0 + sl]);
      const float cvr[4] = {cv.x, cv.y, cv.z, cv.w};
#pragma unroll
      for (int j = 0; j < 2; ++j) {
        const int dl = w * 32 + j * 16 + l15;
        const float bb = bias[n0 + dl];
        sh4 pw;
#pragma unroll
        for (int r = 0; r < 4; ++r)
          pw[r] = f2bf((acc[i][j][r] + bb) * cvr[r]);
        *reinterpret_cast<sh4*>(&Ls[dl * 88 + sl]) = pw;
      }
    }
    __syncthreads();
    {
      const int row = tid >> 1, seg = tid & 1;  // 128 d-rows, 2 x 64B segs
      const int bh = b * 16 + (n0v >> 6) + (row >> 6);
      const int d = row & 63;
      const short8* src = reinterpret_cast<const short8*>(&Ls[row * 88 + seg * 32]);
      short8* dst = reinterpret_cast<short8*>(
          &vT[((size_t)(bh * HD + d)) * TT + s_batch + seg * 32]);
#pragma unroll
      for (int t = 0; t < 4; ++t) dst[t] = src[t];
    }
    return;
  }

#pragma unroll
  for (int i = 0; i < 4; ++i) {
#pragma unroll
    for (int r = 0; r < 4; ++r) {
      const int row = m0 + i * 16 + quad * 4 + r;
#pragma unroll
      for (int j = 0; j < 2; ++j) {
        const int col = n0 + w * 32 + j * 16 + l15;
        float v = acc[i][j][r] + bias[col];
        // 0.125 * log2(e): fold attn scale AND exp->exp2 domain change into q
        if (col < QS) v *= 0.18033688011112042f;
        if (OUT_BF16)
          ((short*)C)[(size_t)row * N + col] = f2bf(v);
        else
          ((float*)C)[(size_t)row * N + col] = v;
      }
    }
  }
}

__global__ __launch_bounds__(256) void gemm_qkv(
    const short* __restrict__ A, const short* __restrict__ Bt,
    const float* __restrict__ bias, void* __restrict__ C,
    short* __restrict__ vT, const float* __restrict__ cV, int M, int N, int K,
    int QS) {
  gemm_bt_body<true>(A, Bt, bias, C, vT, cV, M, N, K, QS);
}

__global__ __launch_bounds__(256) void gemm_proj(
    const short* __restrict__ A, const short* __restrict__ Bt,
    const float* __restrict__ bias, void* __restrict__ C, int M, int N,
    int K) {
  gemm_bt_body<false>(A, Bt, bias, C, nullptr, nullptr, M, N, K, 0);
}

// ---------------------------------------------------------------------------
// MFMA flash attention v12: NO LDS STAGING, NO BARRIERS. r11 analysis: v8-v11
// all pinned at ~49.5us with SQ_LDS_BANK_CONFLICT exactly constant; LDS-pipe
// budget (8 waves x ~20 ds_read_b128 x 12cy + conflicts ~ 90% of the 3600
// cyc/iter slot) -> LDS-bandwidth-bound, K/V read 4x redundantly per block.
// K/V is L2-resident (FETCH=12MB), so per guide m169: read K/V/c fragments
// DIRECTLY from global into registers (64B-contiguous per 16-lane group,
// L2 hits). Only the per-wave-private P roundtrip stays in LDS -> zero
// cross-wave sharing -> all __syncthreads removed; waves free-run. K
// fragments prefetched one tile ahead by reloading dead regs after QK.
// Math/accumulation order identical to verified v10.
// ---------------------------------------------------------------------------
#define PST 72
__global__ __launch_bounds__(256) void attn_mfma12(
    const short* __restrict__ qkv, const short* __restrict__ vT,
    const short* __restrict__ cb16, short* __restrict__ y) {
  __shared__ __align__(16) short Ps[64 * PST];  // P [q_local][s] (only LDS)
  const int tid = threadIdx.x;
  const int w = tid >> 6, lane = tid & 63;
  const int quad = lane >> 4, l15 = lane & 15;
  const int bh = blockIdx.x, b = bh >> 4, h = bh & 15;  // XCD swizzle: x=bh
  const int px = blockIdx.y;          // 0..15
  const int qh = 31 - px;             // heavy q-tile (64 rows)
  const int nth = qh + 1;
  const int ntot = nth + px + 1;      // == 33, uniform
  const int RS = 3 * CC;

  int qt = qh;                        // current q-tile
  int qrow0 = qt * 64 + w * 16;

  short8 qf0, qf1;
  {
    const size_t qrow = (size_t)(b * TT + qrow0 + l15) * RS + h * HD + quad * 8;
    qf0 = *reinterpret_cast<const short8*>(&qkv[qrow]);
    qf1 = *reinterpret_cast<const short8*>(&qkv[qrow + 32]);
  }

  f32x4 l_acc = {};
  f32x4 o_acc[4] = {};

  // global fragment bases (per-lane)
  const short* kgb = qkv + (size_t)b * TT * RS + CC + h * HD + quad * 8;
  const short* vgb = vT + (size_t)bh * HD * TT + quad * 8;
  const short* cgb = cb16 + b * TT + quad * 8;
  short* psrow = &Ps[(w * 16 + l15) * PST];
  const int kfo0 = quad * 8, kfo1 = 32 + quad * 8;

  // K fragments for tile 0 (prefetched; reloaded for it+1 right after QK)
  short8 kf[4][2];
#pragma unroll
  for (int j = 0; j < 4; ++j) {
    const short* kp = kgb + (size_t)(j * 16 + l15) * RS;
    kf[j][0] = *reinterpret_cast<const short8*>(kp);
    kf[j][1] = *reinterpret_cast<const short8*>(kp + 32);
  }

  for (int it = 0; it < ntot; ++it) {
    const int kt = (it < nth) ? it : it - nth;
    const int s0 = kt * 64;

    if (it == nth) {
      // flush heavy-phase output, reset for light q-tile (per-wave, no sync)
#pragma unroll
      for (int r = 0; r < 4; ++r) {
        const float inv = 1.0f / l_acc[r];
        const size_t row = (size_t)(b * TT + qrow0 + quad * 4 + r);
#pragma unroll
        for (int t = 0; t < 4; ++t)
          y[row * CC + h * HD + t * 16 + l15] = f2bf(o_acc[t][r] * inv);
      }
      qt = px;
      qrow0 = qt * 64 + w * 16;
      const size_t qrow = (size_t)(b * TT + qrow0 + l15) * RS + h * HD + quad * 8;
      qf0 = *reinterpret_cast<const short8*>(&qkv[qrow]);
      qf1 = *reinterpret_cast<const short8*>(&qkv[qrow + 32]);
      l_acc = f32x4{0.f, 0.f, 0.f, 0.f};
#pragma unroll
      for (int t = 0; t < 4; ++t) o_acc[t] = f32x4{0.f, 0.f, 0.f, 0.f};
    }

    // V + c fragments for THIS tile: issued now, consumed after QK+exp
    // (vmcnt wait lands late; L2-hit latency hidden under compute).
    short8 vf[4][2];
#pragma unroll
    for (int t = 0; t < 4; ++t) {
      const short* vp = vgb + (size_t)(t * 16 + l15) * TT + s0;
      vf[t][0] = *reinterpret_cast<const short8*>(vp);
      vf[t][1] = *reinterpret_cast<const short8*>(vp + 32);
    }
    const short8 cf0 = *reinterpret_cast<const short8*>(cgb + s0);
    const short8 cf1 = *reinterpret_cast<const short8*>(cgb + s0 + 32);

    // S^T = K Q'^T : 16 q cols (l15), 64 key rows (j*16+quad*4+r)
    f32x4 sa[4] = {};
#pragma unroll
    for (int j = 0; j < 4; ++j) {
      sa[j] = MFMA16(kf[j][0], qf0, sa[j], 0, 0, 0);
      sa[j] = MFMA16(kf[j][1], qf1, sa[j], 0, 0, 0);
    }

    // kf dead -> prefetch K for the NEXT tile (overlaps exp+PV below)
    if (it + 1 < ntot) {
      const int ktn = (it + 1 == nth) ? 0 : kt + 1;
#pragma unroll
      for (int j = 0; j < 4; ++j) {
        const short* kp = kgb + (size_t)(ktn * 64 + j * 16 + l15) * RS;
        kf[j][0] = *reinterpret_cast<const short8*>(kp);
        kf[j][1] = *reinterpret_cast<const short8*>(kp + 32);
      }
    }

    // p = exp2(s') (mask folded into V/c); boundary tiles apply causal.
    const bool boundary = (kt == qt);
    const int qg = qrow0 + l15;
#pragma unroll
    for (int j = 0; j < 4; ++j) {
      float pv[4];
#pragma unroll
      for (int r = 0; r < 4; ++r) {
        float v = sa[j][r];
        if (boundary) {
          const int sg = s0 + j * 16 + quad * 4 + r;
          if (sg > qg) v = -10000.0f;
        }
        pv[r] = EXP2(v);
      }
      union { __hip_bfloat162 h2[2]; uint2v u; } pk;
      pk.h2[0] = __float22bfloat162_rn(make_float2(pv[0], pv[1]));
      pk.h2[1] = __float22bfloat162_rn(make_float2(pv[2], pv[3]));
      *reinterpret_cast<uint2v*>(&psrow[j * 16 + quad * 4]) = pk.u;
    }

    // O += P V'   and   l += P c  (same-wave P roundtrip; in-order LDS)
    const short8 pf0 = *reinterpret_cast<const short8*>(&psrow[kfo0]);
    const short8 pf1 = *reinterpret_cast<const short8*>(&psrow[kfo1]);
    l_acc = MFMA16(pf0, cf0, l_acc, 0, 0, 0);
    l_acc = MFMA16(pf1, cf1, l_acc, 0, 0, 0);
#pragma unroll
    for (int t = 0; t < 4; ++t) {
      o_acc[t] = MFMA16(pf0, vf[t][0], o_acc[t], 0, 0, 0);
      o_acc[t] = MFMA16(pf1, vf[t][1], o_acc[t], 0, 0, 0);
    }
  }

  // flush light-phase output
#pragma unroll
  for (int r = 0; r < 4; ++r) {
    const float inv = 1.0f / l_acc[r];
    const size_t row = (size_t)(b * TT + qrow0 + quad * 4 + r);
#pragma unroll
    for (int t = 0; t < 4; ++t)
      y[row * CC + h * HD + t * 16 + l15] = f2bf(o_acc[t][r] * inv);
  }
}

extern "C" void kernel_launch(void* const* d_in, const int* in_sizes, int n_in,
                              void* d_out, int out_size, void* d_ws,
                              size_t ws_size, hipStream_t stream) {
  const float* x = (const float*)d_in[0];
  const float* attn_mask = (const float*)d_in[1];
  const float* W_attn = (const float*)d_in[2];
  const float* b_attn = (const float*)d_in[3];
  const float* W_proj = (const float*)d_in[4];
  const float* b_proj = (const float*)d_in[5];
  float* out = (float*)d_out;

  const int M = BATCH * TT;  // 4096

  short* xb = (short*)d_ws;                       // [4096,1024]
  short* wat = xb + (size_t)M * CC;               // [3072,1024]
  short* wpt = wat + (size_t)(3 * CC) * CC;       // [1024,1024]
  short* qkvb = wpt + (size_t)CC * CC;            // [4096,3072] (v third unused)
  short* yb = qkvb + (size_t)M * 3 * CC;          // [4096,1024]
  short* vTb = yb + (size_t)M * CC;               // [2*16*64, 2048]
  short* cb16 = vTb + (size_t)BATCH * NH * HD * TT;  // [2,2048] bf16
  float* cf32 = (float*)(cb16 + (size_t)BATCH * TT); // [2,2048] f32

  prep_fused<<<3074, 256, 0, stream>>>(x, xb, W_attn, wat, W_proj, wpt,
                                       attn_mask, cb16, cf32);

  // qkv = x @ W_attn + b_attn; q-third scaled by 0.125*log2e (exp2 fold);
  // v-third scaled by c=exp(mask), written transposed into vTb. dbuf 2-phase.
  gemm_qkv<<<dim3((3 * CC) / 128, M / 64), 256, 0, stream>>>(
      xb, wat, b_attn, qkvb, vTb, cf32, M, 3 * CC, CC, CC);

  // attention: diagonal-paired uniform blocks; grid (bh, px) XCD-local K/V;
  // register-direct K/V/c (no LDS staging, no barriers).
  attn_mfma12<<<dim3(BATCH * NH, 16), 256, 0, stream>>>(
      qkvb, vTb, cb16, yb);

  // out = y @ W_proj + b_proj. dbuf 2-phase.
  gemm_proj<<<dim3(CC / 128, M / 64), 256, 0, stream>>>(
      yb, wpt, b_proj, out, M, CC, CC);
}

// Round 13
// 181.190 us; speedup vs baseline: 1.4468x; 1.4468x over previous
//
#include <hip/hip_runtime.h>
#include <hip/hip_bf16.h>
#include <stdint.h>

#define BATCH 2
#define TT 2048
#define CC 1024
#define NH 16
#define HD 64

typedef __attribute__((ext_vector_type(8))) short short8;
typedef __attribute__((ext_vector_type(4))) short sh4;
typedef __attribute__((ext_vector_type(4))) float f32x4;
typedef __attribute__((ext_vector_type(2))) unsigned uint2v;

#define MFMA16 __builtin_amdgcn_mfma_f32_16x16x32_bf16
#define LOG2E 1.4426950408889634f

#if defined(__has_builtin)
#if __has_builtin(__builtin_amdgcn_exp2f)
#define EXP2(x) __builtin_amdgcn_exp2f(x)
#else
#define EXP2(x) __expf((x) * 0.6931471805599453f)
#endif
#else
#define EXP2(x) __expf((x) * 0.6931471805599453f)
#endif

__device__ __forceinline__ short f2bf(float f) {
  union { float f; unsigned u; } x;
  x.f = f;
  unsigned r = x.u + 0x7FFFu + ((x.u >> 16) & 1u);
  return (short)(r >> 16);
}

// ---------------------------------------------------------------------------
// Fused prep: blocks [0,2048) cast x fp32->bf16; [2048,2816) transpose W_attn;
// [2816,3072) transpose W_proj; [3072,3074) c = exp(mask) tables (bf16+f32).
// ---------------------------------------------------------------------------
__device__ __forceinline__ void transpose_cast_tile(
    const float* __restrict__ W, short* __restrict__ Wt, int K, int N,
    int n0, int k0, int tid) {
  __shared__ __align__(16) float Ls[64][68];
  {
    const int r = tid >> 4, c4 = (tid & 15) * 4;
#pragma unroll
    for (int p = 0; p < 4; ++p) {
      const float4 v = *reinterpret_cast<const float4*>(
          &W[(size_t)(k0 + r + p * 16) * N + n0 + c4]);
      *reinterpret_cast<float4*>(&Ls[r + p * 16][c4]) = v;
    }
  }
  __syncthreads();
  {
    const int n = tid >> 2;
    const int kk0 = (tid & 3) * 16;
#pragma unroll
    for (int half = 0; half < 2; ++half) {
      short8 o;
#pragma unroll
      for (int t = 0; t < 8; ++t) o[t] = f2bf(Ls[kk0 + half * 8 + t][n]);
      *reinterpret_cast<short8*>(&Wt[(size_t)(n0 + n) * K + k0 + kk0 + half * 8]) = o;
    }
  }
}

__global__ __launch_bounds__(256) void prep_fused(
    const float* __restrict__ x, short* __restrict__ xb,
    const float* __restrict__ W_attn, short* __restrict__ wat,
    const float* __restrict__ W_proj, short* __restrict__ wpt,
    const float* __restrict__ mask, short* __restrict__ cb16,
    float* __restrict__ cf32) {
  const int blk = blockIdx.x;
  const int tid = threadIdx.x;
  if (blk < 2048) {
    const int i = (blk * 256 + tid) * 8;
    const float4 a = *reinterpret_cast<const float4*>(&x[i]);
    const float4 b = *reinterpret_cast<const float4*>(&x[i + 4]);
    short8 o;
    o[0] = f2bf(a.x); o[1] = f2bf(a.y); o[2] = f2bf(a.z); o[3] = f2bf(a.w);
    o[4] = f2bf(b.x); o[5] = f2bf(b.y); o[6] = f2bf(b.z); o[7] = f2bf(b.w);
    *reinterpret_cast<short8*>(&xb[i]) = o;
  } else if (blk < 2816) {
    const int b2 = blk - 2048;
    transpose_cast_tile(W_attn, wat, CC, 3 * CC, (b2 % 48) * 64,
                        (b2 / 48) * 64, tid);
  } else if (blk < 3072) {
    const int b3 = blk - 2816;
    transpose_cast_tile(W_proj, wpt, CC, CC, (b3 % 16) * 64, (b3 / 16) * 64,
                        tid);
  } else {
    // c[b][s] = exp(mask[b][s]): bf16 (attn l-row) + f32 (vT scaling)
    const int b = blk - 3072;
    const int s = tid * 8;
    float c[8];
#pragma unroll
    for (int t = 0; t < 8; ++t) c[t] = __expf(mask[b * TT + s + t]);
    short8 o;
#pragma unroll
    for (int t = 0; t < 8; ++t) o[t] = f2bf(c[t]);
    *reinterpret_cast<short8*>(&cb16[b * TT + s]) = o;
#pragma unroll
    for (int t = 0; t < 8; ++t) cf32[b * TT + s + t] = c[t];
  }
}

// ---------------------------------------------------------------------------
// GEMM 64x128 tile, DOUBLE-BUFFERED (T3 minimum 2-phase, verified r8: -10us).
// LDS 48KB. Cols < QS get *(0.125*log2e). V third (n0>=2*CC, vT!=nullptr):
// tile scaled by c[s]=exp(mask) and written TRANSPOSED to vT[bh][d][s].
// ---------------------------------------------------------------------------
template <bool OUT_BF16>
__device__ __forceinline__ void gemm_bt_body(
    const short* __restrict__ A, const short* __restrict__ Bt,
    const float* __restrict__ bias, void* __restrict__ C,
    short* __restrict__ vT, const float* __restrict__ cV, int M, int N, int K,
    int QS) {
  __shared__ __align__(16) short SM[24576];  // 48KB arena
  short* As = SM;            // [2 buf][2 kh][64][32]  = 8192 shorts
  short* Bs = SM + 8192;     // [2 buf][2 kh][128][32] = 16384 shorts
  const int tid = threadIdx.x;
  const int w = tid >> 6, lane = tid & 63;
  const int quad = lane >> 4, l15 = lane & 15;
  const int m0 = blockIdx.y * 64, n0 = blockIdx.x * 128;

  f32x4 acc[4][2] = {};
  const int row16 = lane >> 2;
  const int c4 = (lane & 3) * 8;

  const int rbaseA = __builtin_amdgcn_readfirstlane(w * 16);
  const int rbaseB0 = __builtin_amdgcn_readfirstlane(w * 2 * 16);
  const int rbaseB1 = __builtin_amdgcn_readfirstlane((w * 2 + 1) * 16);

#define STAGE_TILE(buf, k0)                                                    \
  {                                                                            \
    _Pragma("unroll") for (int kh = 0; kh < 2; ++kh) {                         \
      const short* ga =                                                        \
          &A[(size_t)(m0 + rbaseA + row16) * K + (k0) + kh * 32 + c4];         \
      __builtin_amdgcn_global_load_lds(                                        \
          (const __attribute__((address_space(1))) void*)ga,                   \
          (__attribute__((address_space(3))) void*)                            \
              &As[(buf)*4096 + kh * 2048 + rbaseA * 32],                       \
          16, 0, 0);                                                           \
      const short* gb0 =                                                       \
          &Bt[(size_t)(n0 + rbaseB0 + row16) * K + (k0) + kh * 32 + c4];       \
      __builtin_amdgcn_global_load_lds(                                        \
          (const __attribute__((address_space(1))) void*)gb0,                  \
          (__attribute__((address_space(3))) void*)                            \
              &Bs[(buf)*8192 + kh * 4096 + rbaseB0 * 32],                      \
          16, 0, 0);                                                           \
      const short* gb1 =                                                       \
          &Bt[(size_t)(n0 + rbaseB1 + row16) * K + (k0) + kh * 32 + c4];       \
      __builtin_amdgcn_global_load_lds(                                        \
          (const __attribute__((address_space(1))) void*)gb1,                  \
          (__attribute__((address_space(3))) void*)                            \
              &Bs[(buf)*8192 + kh * 4096 + rbaseB1 * 32],                      \
          16, 0, 0);                                                           \
    }                                                                          \
  }

  STAGE_TILE(0, 0)
  __syncthreads();

  int cur = 0;
  for (int k0 = 0; k0 < K; k0 += 64) {
    if (k0 + 64 < K) STAGE_TILE(cur ^ 1, k0 + 64)

    short8 af[2][4], bfr[2][2];
#pragma unroll
    for (int kh = 0; kh < 2; ++kh) {
#pragma unroll
      for (int i = 0; i < 4; ++i)
        af[kh][i] = *reinterpret_cast<const short8*>(
            &As[cur * 4096 + kh * 2048 + (i * 16 + l15) * 32 + quad * 8]);
#pragma unroll
      for (int j = 0; j < 2; ++j)
        bfr[kh][j] = *reinterpret_cast<const short8*>(
            &Bs[cur * 8192 + kh * 4096 + (w * 32 + j * 16 + l15) * 32 +
                quad * 8]);
    }
#pragma unroll
    for (int kh = 0; kh < 2; ++kh)
#pragma unroll
      for (int i = 0; i < 4; ++i)
#pragma unroll
        for (int j = 0; j < 2; ++j)
          acc[i][j] = MFMA16(af[kh][i], bfr[kh][j], acc[i][j], 0, 0, 0);

    __syncthreads();
    cur ^= 1;
  }
#undef STAGE_TILE

  if (OUT_BF16 && vT != nullptr && n0 >= 2 * CC) {
    // V-tile: (acc+bias)*c[s] -> transposed vT[bh][d][s] via LDS.
    const int n0v = n0 - 2 * CC;
    const int b = m0 >> 11;
    const int s_batch = m0 & (TT - 1);
    short* Ls = SM;  // [128][88] = 11264 shorts <= 24576
#pragma unroll
    for (int i = 0; i < 4; ++i) {
      const int sl = i * 16 + quad * 4;
      const float4 cv = *reinterpret_cast<const float4*>(&cV[m0 + sl]);
      const float cvr[4] = {cv.x, cv.y, cv.z, cv.w};
#pragma unroll
      for (int j = 0; j < 2; ++j) {
        const int dl = w * 32 + j * 16 + l15;
        const float bb = bias[n0 + dl];
        sh4 pw;
#pragma unroll
        for (int r = 0; r < 4; ++r)
          pw[r] = f2bf((acc[i][j][r] + bb) * cvr[r]);
        *reinterpret_cast<sh4*>(&Ls[dl * 88 + sl]) = pw;
      }
    }
    __syncthreads();
    {
      const int row = tid >> 1, seg = tid & 1;  // 128 d-rows, 2 x 64B segs
      const int bh = b * 16 + (n0v >> 6) + (row >> 6);
      const int d = row & 63;
      const short8* src = reinterpret_cast<const short8*>(&Ls[row * 88 + seg * 32]);
      short8* dst = reinterpret_cast<short8*>(
          &vT[((size_t)(bh * HD + d)) * TT + s_batch + seg * 32]);
#pragma unroll
      for (int t = 0; t < 4; ++t) dst[t] = src[t];
    }
    return;
  }

#pragma unroll
  for (int i = 0; i < 4; ++i) {
#pragma unroll
    for (int r = 0; r < 4; ++r) {
      const int row = m0 + i * 16 + quad * 4 + r;
#pragma unroll
      for (int j = 0; j < 2; ++j) {
        const int col = n0 + w * 32 + j * 16 + l15;
        float v = acc[i][j][r] + bias[col];
        // 0.125 * log2(e): fold attn scale AND exp->exp2 domain change into q
        if (col < QS) v *= 0.18033688011112042f;
        if (OUT_BF16)
          ((short*)C)[(size_t)row * N + col] = f2bf(v);
        else
          ((float*)C)[(size_t)row * N + col] = v;
      }
    }
  }
}

__global__ __launch_bounds__(256) void gemm_qkv(
    const short* __restrict__ A, const short* __restrict__ Bt,
    const float* __restrict__ bias, void* __restrict__ C,
    short* __restrict__ vT, const float* __restrict__ cV, int M, int N, int K,
    int QS) {
  gemm_bt_body<true>(A, Bt, bias, C, vT, cV, M, N, K, QS);
}

__global__ __launch_bounds__(256) void gemm_proj(
    const short* __restrict__ A, const short* __restrict__ Bt,
    const float* __restrict__ bias, void* __restrict__ C, int M, int N,
    int K) {
  gemm_bt_body<false>(A, Bt, bias, C, nullptr, nullptr, M, N, K, 0);
}

// ---------------------------------------------------------------------------
// MFMA flash attention v13: v10 structure (verified best) + 2x2 WAVE
// PARTITION. r12 falsified LDS-aggregate-BW AND global-direct theories; the
// remaining candidate is the per-wave LDS issue/latency chain (each of 4
// waves redundantly read the whole 8KB K + 8KB V tile = 20 b128/iter).
// Wave w=(qb,kb) now owns a 32q x 32key quadrant: reads 4 K-frag + 4 V-frag
// + 2 P + 1 c = 11 b128/iter. O/l become key-partial per wave -> 3-barrier
// LDS combine (scratch = dead Ks arena) at the 2 flushes only. Same MFMA
// count, staging, and per-(q,key) accumulation order as v10.
// ---------------------------------------------------------------------------
#define PST 72
__global__ __launch_bounds__(256) void attn_mfma13(
    const short* __restrict__ qkv, const short* __restrict__ vT,
    const short* __restrict__ cb16, short* __restrict__ y) {
  __shared__ __align__(16) short Ks[2][64 * PST];
  __shared__ __align__(16) short Vs[2][64 * PST];  // V'^T [d][s] (c-scaled)
  __shared__ __align__(16) short Ps[64 * PST];     // P [q 64][key 64]
  __shared__ __align__(16) short Cs[2][64];        // c-row per s-tile
  __shared__ float Lsc[64];                        // l-partial exchange
  const int tid = threadIdx.x;
  const int w = tid >> 6, lane = tid & 63;
  const int qb = w >> 1, kb = w & 1;               // 2x2 wave grid
  const int quad = lane >> 4, l15 = lane & 15;
  const int bh = blockIdx.x, b = bh >> 4, h = bh & 15;  // XCD swizzle: x=bh
  const int px = blockIdx.y;          // 0..15
  const int qh = 31 - px;             // heavy q-tile (64 rows)
  const int nth = qh + 1;
  const int ntot = nth + px + 1;      // == 33, uniform
  const int RS = 3 * CC;

  int qt = qh;                        // current q-tile
  int qrow0b = qt * 64 + qb * 32;     // this wave's 32-row q base

  // Q fragments: qf[j][c], j = 16-row q-sub, c = 32-wide d-chunk
  short8 qf[2][2];
#pragma unroll
  for (int j = 0; j < 2; ++j) {
    const size_t qrow =
        (size_t)(b * TT + qrow0b + j * 16 + l15) * RS + h * HD + quad * 8;
    qf[j][0] = *reinterpret_cast<const short8*>(&qkv[qrow]);
    qf[j][1] = *reinterpret_cast<const short8*>(&qkv[qrow + 32]);
  }

  f32x4 l_acc[2] = {};
  f32x4 o_acc[2][4] = {};

  const int sr = tid >> 3, sc = (tid & 7) * 8;
  const short* kbase = qkv + (size_t)(b * TT + sr) * RS + CC + h * HD + sc;
  const short* vbase = vT + (size_t)(bh * HD + sr) * TT + sc;
  const short* cbase = cb16 + b * TT;

  // flush: kb=1 waves export key-partials via dead Ks arena; kb=0 combine.
  auto flush_combine = [&]() {
    __syncthreads();  // all waves done with previous compute (Ks/Vs dead)
    float* oscr = reinterpret_cast<float*>(&Ks[0][0]) + qb * (32 * 68);
    if (kb == 1) {
#pragma unroll
      for (int j = 0; j < 2; ++j)
#pragma unroll
        for (int t = 0; t < 4; ++t)
#pragma unroll
          for (int r = 0; r < 4; ++r)
            oscr[(j * 16 + quad * 4 + r) * 68 + t * 16 + l15] = o_acc[j][t][r];
      if (l15 == 0) {
#pragma unroll
        for (int j = 0; j < 2; ++j)
#pragma unroll
          for (int r = 0; r < 4; ++r)
            Lsc[qb * 32 + j * 16 + quad * 4 + r] = l_acc[j][r];
      }
    }
    __syncthreads();
    if (kb == 0) {
#pragma unroll
      for (int j = 0; j < 2; ++j) {
#pragma unroll
        for (int r = 0; r < 4; ++r) {
          const float lsum = l_acc[j][r] + Lsc[qb * 32 + j * 16 + quad * 4 + r];
          const float inv = 1.0f / lsum;
          const size_t row = (size_t)(b * TT + qrow0b + j * 16 + quad * 4 + r);
#pragma unroll
          for (int t = 0; t < 4; ++t) {
            const float v =
                o_acc[j][t][r] + oscr[(j * 16 + quad * 4 + r) * 68 + t * 16 + l15];
            y[row * CC + h * HD + t * 16 + l15] = f2bf(v * inv);
          }
        }
      }
    }
    __syncthreads();  // protect scratch from the next staging writes
  };

  // prefetch s-tile 0
  short8 kpre0 = *reinterpret_cast<const short8*>(kbase);
  short8 kpre1 = *reinterpret_cast<const short8*>(kbase + (size_t)32 * RS);
  short8 vpre0 = *reinterpret_cast<const short8*>(vbase);
  short8 vpre1 = *reinterpret_cast<const short8*>(vbase + 32 * TT);
  short8 cpre = {};
  if (tid < 8) cpre = *reinterpret_cast<const short8*>(&cbase[tid * 8]);

  for (int it = 0; it < ntot; ++it) {
    const int kt = (it < nth) ? it : it - nth;
    const int s0 = kt * 64;

    if (it == nth) {
      flush_combine();
      qt = px;
      qrow0b = qt * 64 + qb * 32;
#pragma unroll
      for (int j = 0; j < 2; ++j) {
        const size_t qrow =
            (size_t)(b * TT + qrow0b + j * 16 + l15) * RS + h * HD + quad * 8;
        qf[j][0] = *reinterpret_cast<const short8*>(&qkv[qrow]);
        qf[j][1] = *reinterpret_cast<const short8*>(&qkv[qrow + 32]);
      }
      l_acc[0] = l_acc[1] = f32x4{0.f, 0.f, 0.f, 0.f};
#pragma unroll
      for (int j = 0; j < 2; ++j)
#pragma unroll
        for (int t = 0; t < 4; ++t) o_acc[j][t] = f32x4{0.f, 0.f, 0.f, 0.f};
    }

    const int cur = it & 1;
    *reinterpret_cast<short8*>(&Ks[cur][sr * PST + sc]) = kpre0;
    *reinterpret_cast<short8*>(&Ks[cur][(sr + 32) * PST + sc]) = kpre1;
    *reinterpret_cast<short8*>(&Vs[cur][sr * PST + sc]) = vpre0;
    *reinterpret_cast<short8*>(&Vs[cur][(sr + 32) * PST + sc]) = vpre1;
    if (tid < 8) *reinterpret_cast<short8*>(&Cs[cur][tid * 8]) = cpre;
    __syncthreads();

    // prefetch tile it+1 (hides behind compute)
    if (it + 1 < ntot) {
      const int ktn = (it + 1 == nth) ? 0 : kt + 1;
      const short* kp = kbase + (size_t)ktn * 64 * RS;
      const short* vp = vbase + ktn * 64;
      kpre0 = *reinterpret_cast<const short8*>(kp);
      kpre1 = *reinterpret_cast<const short8*>(kp + (size_t)32 * RS);
      vpre0 = *reinterpret_cast<const short8*>(vp);
      vpre1 = *reinterpret_cast<const short8*>(vp + 32 * TT);
      if (tid < 8)
        cpre = *reinterpret_cast<const short8*>(&cbase[ktn * 64 + tid * 8]);
    }

    // S^T quadrant: keys kb*32+{0..31} x q qb*32+{0..31}
    f32x4 sa[2][2] = {};
#pragma unroll
    for (int i = 0; i < 2; ++i) {
      const short8 kf0 = *reinterpret_cast<const short8*>(
          &Ks[cur][(kb * 32 + i * 16 + l15) * PST + quad * 8]);
      const short8 kf1 = *reinterpret_cast<const short8*>(
          &Ks[cur][(kb * 32 + i * 16 + l15) * PST + 32 + quad * 8]);
#pragma unroll
      for (int j = 0; j < 2; ++j) {
        sa[i][j] = MFMA16(kf0, qf[j][0], sa[i][j], 0, 0, 0);
        sa[i][j] = MFMA16(kf1, qf[j][1], sa[i][j], 0, 0, 0);
      }
    }

    // p = exp2(s'); boundary tiles apply causal. Store own P quadrant.
    const bool boundary = (kt == qt);
#pragma unroll
    for (int j = 0; j < 2; ++j) {
      const int qg = qrow0b + j * 16 + l15;
      short* psrow = &Ps[(size_t)(qb * 32 + j * 16 + l15) * PST];
#pragma unroll
      for (int i = 0; i < 2; ++i) {
        float pv[4];
#pragma unroll
        for (int r = 0; r < 4; ++r) {
          float v = sa[i][j][r];
          if (boundary) {
            const int sg = s0 + kb * 32 + i * 16 + quad * 4 + r;
            if (sg > qg) v = -10000.0f;
          }
          pv[r] = EXP2(v);
        }
        union { __hip_bfloat162 h2[2]; uint2v u; } pk;
        pk.h2[0] = __float22bfloat162_rn(make_float2(pv[0], pv[1]));
        pk.h2[1] = __float22bfloat162_rn(make_float2(pv[2], pv[3]));
        *reinterpret_cast<uint2v*>(&psrow[kb * 32 + i * 16 + quad * 4]) = pk.u;
      }
    }

    // O_partial += P V'  and  l_partial += P c  (own quadrant only)
    const short8 cfr = *reinterpret_cast<const short8*>(
        &Cs[cur][kb * 32 + quad * 8]);
    short8 pf[2];
#pragma unroll
    for (int j = 0; j < 2; ++j) {
      pf[j] = *reinterpret_cast<const short8*>(
          &Ps[(size_t)(qb * 32 + j * 16 + l15) * PST + kb * 32 + quad * 8]);
      l_acc[j] = MFMA16(pf[j], cfr, l_acc[j], 0, 0, 0);
    }
#pragma unroll
    for (int t = 0; t < 4; ++t) {
      const short8 vf = *reinterpret_cast<const short8*>(
          &Vs[cur][(t * 16 + l15) * PST + kb * 32 + quad * 8]);
#pragma unroll
      for (int j = 0; j < 2; ++j)
        o_acc[j][t] = MFMA16(pf[j], vf, o_acc[j][t], 0, 0, 0);
    }
  }

  flush_combine();
}

extern "C" void kernel_launch(void* const* d_in, const int* in_sizes, int n_in,
                              void* d_out, int out_size, void* d_ws,
                              size_t ws_size, hipStream_t stream) {
  const float* x = (const float*)d_in[0];
  const float* attn_mask = (const float*)d_in[1];
  const float* W_attn = (const float*)d_in[2];
  const float* b_attn = (const float*)d_in[3];
  const float* W_proj = (const float*)d_in[4];
  const float* b_proj = (const float*)d_in[5];
  float* out = (float*)d_out;

  const int M = BATCH * TT;  // 4096

  short* xb = (short*)d_ws;                       // [4096,1024]
  short* wat = xb + (size_t)M * CC;               // [3072,1024]
  short* wpt = wat + (size_t)(3 * CC) * CC;       // [1024,1024]
  short* qkvb = wpt + (size_t)CC * CC;            // [4096,3072] (v third unused)
  short* yb = qkvb + (size_t)M * 3 * CC;          // [4096,1024]
  short* vTb = yb + (size_t)M * CC;               // [2*16*64, 2048]
  short* cb16 = vTb + (size_t)BATCH * NH * HD * TT;  // [2,2048] bf16
  float* cf32 = (float*)(cb16 + (size_t)BATCH * TT); // [2,2048] f32

  prep_fused<<<3074, 256, 0, stream>>>(x, xb, W_attn, wat, W_proj, wpt,
                                       attn_mask, cb16, cf32);

  // qkv = x @ W_attn + b_attn; q-third scaled by 0.125*log2e (exp2 fold);
  // v-third scaled by c=exp(mask), written transposed into vTb. dbuf 2-phase.
  gemm_qkv<<<dim3((3 * CC) / 128, M / 64), 256, 0, stream>>>(
      xb, wat, b_attn, qkvb, vTb, cf32, M, 3 * CC, CC, CC);

  // attention: diagonal-paired uniform blocks; grid (bh, px) XCD-local K/V;
  // 2x2 wave partition (halved per-wave LDS chain) + flush combine.
  attn_mfma13<<<dim3(BATCH * NH, 16), 256, 0, stream>>>(
      qkvb, vTb, cb16, yb);

  // out = y @ W_proj + b_proj. dbuf 2-phase.
  gemm_proj<<<dim3(CC / 128, M / 64), 256, 0, stream>>>(
      yb, wpt, b_proj, out, M, CC, CC);
}